// Round 3
// baseline (281.077 us; speedup 1.0000x reference)
//
#include <hip/hip_runtime.h>
#include <math.h>

#define NF 16
#define VOCAB 100000
#define S1 28      // conv1 plane stride, dwords per pair-row (112 B)
#define NP1 31     // pair-rows per conv1 plane
#define PB 868     // plane B base (dwords) = NP1*S1
#define S2 20      // conv2 plane stride, dwords per row (80 B)
#define F1B 1736   // filter1 LDS base (dwords), 16B aligned
#define F2B 1992   // filter2 LDS base (dwords), 16B aligned
#define LDSW 2376  // total LDS dwords

typedef _Float16 h2 __attribute__((ext_vector_type(2)));

#if __has_builtin(__builtin_amdgcn_fdot2)
#define FDOT2(a, b, c) __builtin_amdgcn_fdot2((a), (b), (c), false)
#else
#define FDOT2(a, b, c) ((float)(a)[0] * (float)(b)[0] + ((float)(a)[1] * (float)(b)[1] + (c)))
#endif

__device__ __forceinline__ float tanhf_fast(float x) {
    float e = __expf(2.f * x);
    return 1.f - 2.f * __builtin_amdgcn_rcpf(e + 1.f);
}

__device__ __forceinline__ h2 u2h(unsigned int u) {
    union { unsigned int u; h2 h; } c; c.u = u; return c.h;
}

// Single kernel: no pack_filters pre-pass, no d_ws use. Each block packs the
// (tiny, L2-resident) filter tables into its own LDS:
//   lds[F1B + j*16 + kw*2 + o]  = {f1[2j][kw][0][o],   f1[2j+1][kw][0][o]}   j<16, rows of 16 (14 used)
//   lds[F2B + kh*12 + kw*2 + o] = {f2[kh][kw][0][o],   f2[kh][kw][1][o]}     kh<32, rows of 12 (10 used)
__global__ __launch_bounds__(64, 4) void ccpm_fwd(
    const int* __restrict__ idx,
    const float* __restrict__ w0,
    const float* __restrict__ b0,
    const float* __restrict__ f1g,
    const float* __restrict__ f2g,
    const float* __restrict__ w1,
    const float* __restrict__ b1,
    float* __restrict__ out)
{
    const int b = blockIdx.x;
    const int l = threadIdx.x;

    __shared__ __align__(16) unsigned int lds[LDSW];

    const float4 z4 = make_float4(0.f, 0.f, 0.f, 0.f);

    // ---- phase 0a: issue the embedding gather FIRST (longest-latency chain:
    //      idx load -> dependent w0 row load). Filter packing + plane zeroing
    //      below execute while these are in flight. ----
    const int f  = l >> 2;            // 0..15
    const int e0 = (l & 3) * 8;       // 0,8,16,24
    const int row = idx[b * NF + f];
    const float4* src = (const float4*)(w0 + ((size_t)f * VOCAB + row) * 32 + e0);
    const float4* bb  = (const float4*)(b0 + f * 32 + e0);
    float4 v0 = src[0], v1 = src[1];
    float4 u0 = bb[0],  u1 = bb[1];

    // ---- phase 0b: pack f1 -> LDS (224 entries over 256 padded slots) ----
    #pragma unroll
    for (int i = 0; i < 4; ++i) {
        int n = i * 64 + l;           // 0..255
        int j = n >> 4, r = n & 15;
        if (r < 14) {
            int kw = r >> 1, o = r & 1;
            h2 h;
            h[0] = (_Float16)f1g[(14 * j + kw) * 2 + o];      // f1[2j  ][kw][0][o]
            h[1] = (_Float16)f1g[(14 * j + 7 + kw) * 2 + o];  // f1[2j+1][kw][0][o]
            union { h2 h; unsigned int u; } c; c.h = h;
            lds[F1B + n] = c.u;
        }
    }
    // ---- phase 0c: pack f2 -> LDS (320 entries over 384 padded slots) ----
    #pragma unroll
    for (int i = 0; i < 6; ++i) {
        int n = i * 64 + l;           // 0..383
        int kh = n / 12, r = n - kh * 12;
        if (r < 10) {
            int kw = r >> 1, o = r & 1;
            h2 h;
            h[0] = (_Float16)f2g[(kh * 5 + kw) * 4 + o];      // f2[kh][kw][0][o]
            h[1] = (_Float16)f2g[(kh * 5 + kw) * 4 + 2 + o];  // f2[kh][kw][1][o]
            union { h2 h; unsigned int u; } c; c.h = h;
            lds[F2B + n] = c.u;
        }
    }
    // ---- phase 0d: zero both conv1 planes ----
    #pragma unroll
    for (int i = 0; i < 7; ++i) {
        int n = i * 64 + l;
        if (n < F1B / 4) ((float4*)lds)[n] = z4;
    }
    __syncthreads();

    // ---- phase 1: embedding gather + bias + tanh -> both row-interleaved planes ----
    {
        float g[8];
        g[0]=v0.x+u0.x; g[1]=v0.y+u0.y; g[2]=v0.z+u0.z; g[3]=v0.w+u0.w;
        g[4]=v1.x+u1.x; g[5]=v1.y+u1.y; g[6]=v1.z+u1.z; g[7]=v1.w+u1.w;
        _Float16* H = (_Float16*)lds;
        const int C = f + 3;
        #pragma unroll
        for (int i = 0; i < 8; ++i) {
            int R = e0 + i + 15;                 // padded row, 15..46
            _Float16 hv = (_Float16)tanhf_fast(g[i]);
            H[((R >> 1) * S1 + C) * 2 + (R & 1)] = hv;          // plane A (rows 2pr,2pr+1)
            int prB = (R & 1) ? (R >> 1) : (R >> 1) - 1;        // plane B (rows 2pr+1,2pr+2)
            H[(PB + prB * S1 + C) * 2 + ((R & 1) ^ 1)] = hv;
        }
    }
    __syncthreads();

    const int h  = l >> 1;          // output row e, 0..31
    const int wh = l & 1;

    // ---- phase 2: conv1 (32x7 SAME), kh-paired dot2, filters from LDS (broadcast) ----
    float a0[8], a1[8];
    {
        #pragma unroll
        for (int w = 0; w < 8; ++w) { a0[w] = 0.f; a1[w] = 0.f; }
        const unsigned int* plane = lds + ((h & 1) ? PB : 0);
        const int pr0 = h >> 1;
        const int wb  = wh * 8;
        #pragma unroll 2
        for (int j = 0; j < 16; ++j) {           // kh pair (2j, 2j+1)
            const uint4* rp = (const uint4*)(plane + (pr0 + j) * S1 + wb);
            uint4 q0 = rp[0], q1 = rp[1], q2 = rp[2], q3 = rp[3];
            const uint4* fp4 = (const uint4*)(lds + F1B + j * 16);
            uint4 fA = fp4[0], fB = fp4[1], fC = fp4[2];
            uint2 fD = *(const uint2*)(lds + F1B + j * 16 + 12);
            unsigned int win[16] = {q0.x,q0.y,q0.z,q0.w, q1.x,q1.y,q1.z,q1.w,
                                    q2.x,q2.y,q2.z,q2.w, q3.x,q3.y,q3.z,q3.w};
            unsigned int fv[14] = {fA.x,fA.y,fA.z,fA.w, fB.x,fB.y,fB.z,fB.w,
                                   fC.x,fC.y,fC.z,fC.w, fD.x,fD.y};
            #pragma unroll
            for (int kw = 0; kw < 7; ++kw) {
                h2 f0 = u2h(fv[kw * 2 + 0]);
                h2 f1h = u2h(fv[kw * 2 + 1]);
                #pragma unroll
                for (int w = 0; w < 8; ++w) {
                    h2 wv = u2h(win[w + kw]);
                    a0[w] = FDOT2(wv, f0, a0[w]);
                    a1[w] = FDOT2(wv, f1h, a1[w]);
                }
            }
        }
    }
    __syncthreads();

    // ---- phase 3: re-zero conv2 plane region (63 rows x S2 dwords) ----
    #pragma unroll
    for (int i = 0; i < 5; ++i) {
        int n = i * 64 + l;
        if (n < (63 * S2) / 4) ((float4*)lds)[n] = z4;
    }
    __syncthreads();

    // ---- phase 4: pool1 top-8 of 16 -> conv2 plane, i-channels packed per dword ----
    {
        float own[8], recv[8];
        #pragma unroll
        for (int i = 0; i < 8; ++i) {
            own[i]  = wh ? a1[i] : a0[i];
            recv[i] = __shfl_xor(wh ? a0[i] : a1[i], 1, 64);
        }
        float v[16];
        #pragma unroll
        for (int i = 0; i < 8; ++i) {
            v[i]     = wh ? recv[i] : own[i];
            v[8 + i] = wh ? own[i] : recv[i];
        }
        int r[16];
        #pragma unroll
        for (int i = 0; i < 16; ++i) r[i] = 0;
        #pragma unroll
        for (int i = 0; i < 16; ++i)
            #pragma unroll
            for (int j = i + 1; j < 16; ++j) {
                bool ge = v[i] >= v[j];          // tie -> earlier index wins
                r[j] += ge ? 1 : 0;
                r[i] += ge ? 0 : 1;
            }
        _Float16* H = (_Float16*)lds;
        #pragma unroll
        for (int i = 0; i < 16; ++i)
            if (r[i] < 8)
                H[((h + 15) * S2 + (r[i] + 2)) * 2 + wh] = (_Float16)v[i];
    }
    __syncthreads();

    // ---- phase 5: conv2 (32x5x2 SAME), i-paired dot2, filters from LDS ----
    float c0[4], c1[4];
    {
        #pragma unroll
        for (int w = 0; w < 4; ++w) { c0[w] = 0.f; c1[w] = 0.f; }
        const int wb2 = wh * 4;
        #pragma unroll 2
        for (int kh = 0; kh < 32; ++kh) {
            const uint4* rp = (const uint4*)(lds + (h + kh) * S2 + wb2);
            uint4 qa = rp[0], qb = rp[1];
            const uint4* gp4 = (const uint4*)(lds + F2B + kh * 12);
            uint4 gA = gp4[0], gB = gp4[1];
            uint2 gD = *(const uint2*)(lds + F2B + kh * 12 + 8);
            unsigned int q[8] = {qa.x,qa.y,qa.z,qa.w, qb.x,qb.y,qb.z,qb.w};
            unsigned int gv[10] = {gA.x,gA.y,gA.z,gA.w, gB.x,gB.y,gB.z,gB.w, gD.x,gD.y};
            #pragma unroll
            for (int kw = 0; kw < 5; ++kw) {
                h2 f0 = u2h(gv[kw * 2 + 0]);
                h2 f1h = u2h(gv[kw * 2 + 1]);
                #pragma unroll
                for (int w = 0; w < 4; ++w) {
                    h2 wv = u2h(q[w + kw]);
                    c0[w] = FDOT2(wv, f0, c0[w]);
                    c1[w] = FDOT2(wv, f1h, c1[w]);
                }
            }
        }
    }

    // ---- phase 6: pool2 top-3 of 8 + tanh + dot(w1) + sigmoid ----
    {
        float own[4], recv[4];
        #pragma unroll
        for (int i = 0; i < 4; ++i) {
            own[i]  = wh ? c1[i] : c0[i];
            recv[i] = __shfl_xor(wh ? c0[i] : c1[i], 1, 64);
        }
        float v[8];
        #pragma unroll
        for (int i = 0; i < 4; ++i) {
            v[i]     = wh ? recv[i] : own[i];
            v[4 + i] = wh ? own[i] : recv[i];
        }
        int r[8];
        #pragma unroll
        for (int i = 0; i < 8; ++i) r[i] = 0;
        #pragma unroll
        for (int i = 0; i < 8; ++i)
            #pragma unroll
            for (int j = i + 1; j < 8; ++j) {
                bool ge = v[i] >= v[j];
                r[j] += ge ? 1 : 0;
                r[i] += ge ? 0 : 1;
            }
        float t0 = 0.f, t1 = 0.f, t2 = 0.f;
        #pragma unroll
        for (int i = 0; i < 8; ++i) {
            t0 = (r[i] == 0) ? v[i] : t0;
            t1 = (r[i] == 1) ? v[i] : t1;
            t2 = (r[i] == 2) ? v[i] : t2;
        }
        float s = tanhf_fast(t0) * w1[h * 6 + wh]
                + tanhf_fast(t1) * w1[h * 6 + 2 + wh]
                + tanhf_fast(t2) * w1[h * 6 + 4 + wh];
        #pragma unroll
        for (int off = 32; off; off >>= 1) s += __shfl_xor(s, off, 64);
        if (l == 0) {
            float logit = s + b1[0];
            out[b] = __builtin_amdgcn_rcpf(1.f + __expf(-logit));
        }
    }
}

extern "C" void kernel_launch(void* const* d_in, const int* in_sizes, int n_in,
                              void* d_out, int out_size, void* d_ws, size_t ws_size,
                              hipStream_t stream) {
    const int*   idx = (const int*)d_in[0];
    const float* w0  = (const float*)d_in[1];
    const float* b0  = (const float*)d_in[2];
    const float* f1  = (const float*)d_in[3];
    const float* f2  = (const float*)d_in[4];
    const float* w1  = (const float*)d_in[5];
    const float* b1  = (const float*)d_in[6];
    float* out = (float*)d_out;
    (void)d_ws; (void)ws_size; (void)in_sizes; (void)n_in;

    // BATCH is fixed at 4096 for this problem; out buffer is 4096 floats.
    // out_size==4096 (element convention) or 16384 (byte convention) both
    // resolve to 4096 blocks — never launch past the checked output range.
    int nb = out_size > 4096 ? out_size / 4 : out_size;
    ccpm_fwd<<<nb, 64, 0, stream>>>(idx, w0, b0, f1, f2, w1, b1, out);
}